// Round 12
// baseline (104.865 us; speedup 1.0000x reference)
//
#include <hip/hip_runtime.h>
#include <hip/hip_bf16.h>

typedef __attribute__((ext_vector_type(16))) float f32x16;
typedef __attribute__((ext_vector_type(8))) short short8v;
typedef __attribute__((ext_vector_type(8))) unsigned short ushort8v;

#define T_ROWS 16384
#define H_DIM  4096
#define E_NUM  64
#define TOPK   8
#define MROWS  32                 // rows per block
#define KC     64                 // k-chunk (floats)
#define NCHB   32                 // chunks per block (covers K-half 2048)
#define WCH    16384              // bytes per W chunk image (frag-ordered)
#define MASK_OFF ((size_t)64 * WCH)            // 1 MB image, then mask
#define PART_OFF (MASK_OFF + 256)              // then 4 MB partial (s=1)

__device__ __forceinline__ unsigned short f2bf(float f) {
    unsigned int u = __float_as_uint(f);
    unsigned int r = (u + 0x7fffu + ((u >> 16) & 1u)) >> 16;  // RNE
    return (unsigned short)r;
}
__device__ __forceinline__ float bf2f(unsigned short h) {
    return __uint_as_float(((unsigned int)h) << 16);
}

// ---- prep: frag-ordered W image + allowed-mask ----
// image[ch 0..63][role w 0..3][lane 0..63][slot j 0..3]*16B
// slot j: ks=j>>1, plane=j&1 (hi/lo). Role w: cg=w&1, kh2=w>>1.
// value: 8 bf16 of W[cg*32+(lane&31)][ch*64 + kh2*32 + ks*16 + (lane>>5)*8 ..]
__global__ __launch_bounds__(256) void prep_w(
    const float* __restrict__ W, unsigned short* __restrict__ WS,
    const int* __restrict__ ids, int nids)
{
    const int g     = blockIdx.x * 256 + threadIdx.x;   // 65536 groups
    const int byteo = g * 16;
    const int ch    = byteo >> 14;
    const int rem   = byteo & 16383;
    const int w     = rem >> 12;
    const int lane  = (rem >> 6) & 63;
    const int j     = (rem >> 4) & 3;
    const int plane = j & 1;
    const int ks    = j >> 1;
    const int row   = (w & 1) * 32 + (lane & 31);
    const int kk    = ch * KC + (w >> 1) * 32 + ks * 16 + (lane >> 5) * 8;
    const float* src = W + (size_t)row * H_DIM + kk;
    ushort8v o;
#pragma unroll
    for (int t = 0; t < 8; ++t) {
        const float f = src[t];
        const unsigned short hb = f2bf(f);
        o[t] = (plane == 0) ? hb : f2bf(f - bf2f(hb));
    }
    *(ushort8v*)((char*)WS + byteo) = o;

    if (blockIdx.x == 0 && threadIdx.x == 0) {
        unsigned long long mb = 0;
        for (int t = 0; t < nids; ++t) {
            const int e = ids[t];
            if (e >= 0 && e < E_NUM) mb |= (1ull << e);
        }
        *(unsigned long long*)((char*)WS + MASK_OFF) = mb;
    }
}

// ---- part: grid 1024 = (row-group g = bid>>1) x (K-half s = bid&1).
// 256 thr = 4 waves; role (cg=w&1, kh2=w>>1): 32x32 partial, B-frags in regs. ----
__global__ __launch_bounds__(256, 4) void router_part(
    const float* __restrict__ X, const unsigned short* __restrict__ WS,
    float* __restrict__ out, float* __restrict__ part1)
{
    const int tid  = threadIdx.x;
    const int lane = tid & 63;
    const int w    = tid >> 6;
    const int cg   = w & 1;
    const int kh2  = w >> 1;
    const int bid  = blockIdx.x;
    const int grp  = bid >> 1;
    const int s    = bid & 1;
    const int rb   = grp * MROWS;
    const int fr32 = lane & 31;
    const int fo   = lane >> 5;

    __shared__ char LDSRAW[17408];
    char* XH = LDSRAW;            // 4 KB [32][128B xor-swizzled]
    char* XL = LDSRAW + 4096;     // 4 KB

    const int srow  = tid >> 3;               // 0..31
    const int sc8   = (tid & 7) * 8;          // f32 col
    const int xbyte = srow * 128 + ((sc8 * 2) ^ ((srow & 7) << 4));
    const float* xg = X + (size_t)(rb + srow) * H_DIM + s * (NCHB * KC) + sc8;
    const char*  wfg = (const char*)WS + (size_t)w * 4096 + lane * 64;
    const int    chimg0 = s * NCHB;

    const int arow = fr32;
    const int asw  = (arow & 7) << 4;

    f32x16 acc;
#pragma unroll
    for (int r = 0; r < 16; ++r) acc[r] = 0.f;

    // prologue: chunk-0 X + B-frags
    float4 px0 = *(const float4*)(xg);
    float4 px1 = *(const float4*)(xg + 4);
    short8v pA0, pA1, pA2, pA3, pB0, pB1, pB2, pB3;
    {
        const char* wi = wfg + (size_t)chimg0 * WCH;
        pA0 = *(const short8v*)(wi);
        pA1 = *(const short8v*)(wi + 16);
        pA2 = *(const short8v*)(wi + 32);
        pA3 = *(const short8v*)(wi + 48);
    }

#define STEP(CH, C0, C1, C2, C3, N0, N1, N2, N3) do {                       \
        __syncthreads();  /* [A] prev compute done; drains VMEM */           \
        {                                                                    \
            float v[8] = {px0.x, px0.y, px0.z, px0.w,                        \
                          px1.x, px1.y, px1.z, px1.w};                       \
            ushort8v hv, lv;                                                 \
            _Pragma("unroll")                                                \
            for (int t = 0; t < 8; ++t) {                                    \
                const unsigned short hb = f2bf(v[t]);                        \
                hv[t] = hb;                                                  \
                lv[t] = f2bf(v[t] - bf2f(hb));                               \
            }                                                                \
            *(ushort8v*)(XH + xbyte) = hv;                                   \
            *(ushort8v*)(XL + xbyte) = lv;                                   \
        }                                                                    \
        __syncthreads();  /* [B] X tile ready */                             \
        if ((CH) + 1 < NCHB) {                                               \
            const float* xn = xg + ((CH) + 1) * KC;                          \
            px0 = *(const float4*)(xn);                                      \
            px1 = *(const float4*)(xn + 4);                                  \
            const char* wi = wfg + (size_t)(chimg0 + (CH) + 1) * WCH;        \
            N0 = *(const short8v*)(wi);                                      \
            N1 = *(const short8v*)(wi + 16);                                 \
            N2 = *(const short8v*)(wi + 32);                                 \
            N3 = *(const short8v*)(wi + 48);                                 \
        }                                                                    \
        {                                                                    \
            const int kb0 = kh2 * 64 + fo * 16;                              \
            short8v ah = *(const short8v*)(XH + arow * 128 + (kb0 ^ asw));   \
            short8v al = *(const short8v*)(XL + arow * 128 + (kb0 ^ asw));   \
            acc = __builtin_amdgcn_mfma_f32_32x32x16_bf16(ah, C0, acc, 0, 0, 0); \
            acc = __builtin_amdgcn_mfma_f32_32x32x16_bf16(ah, C1, acc, 0, 0, 0); \
            acc = __builtin_amdgcn_mfma_f32_32x32x16_bf16(al, C0, acc, 0, 0, 0); \
            const int kb1 = kb0 + 32;                                        \
            short8v ah1 = *(const short8v*)(XH + arow * 128 + (kb1 ^ asw));  \
            short8v al1 = *(const short8v*)(XL + arow * 128 + (kb1 ^ asw));  \
            acc = __builtin_amdgcn_mfma_f32_32x32x16_bf16(ah1, C2, acc, 0, 0, 0); \
            acc = __builtin_amdgcn_mfma_f32_32x32x16_bf16(ah1, C3, acc, 0, 0, 0); \
            acc = __builtin_amdgcn_mfma_f32_32x32x16_bf16(al1, C2, acc, 0, 0, 0); \
        }                                                                    \
    } while (0)

    for (int ch = 0; ch < NCHB; ch += 2) {
        STEP(ch,     pA0, pA1, pA2, pA3, pB0, pB1, pB2, pB3);
        STEP(ch + 1, pB0, pB1, pB2, pB3, pA0, pA1, pA2, pA3);
    }
#undef STEP

    // ---- scoreboard [kh2 2][32][68] f32, deterministic kh2 reduce ----
    __syncthreads();
    float* sm = (float*)LDSRAW;        // 17408 B exactly
    // C/D layout (m74/m101): col = lane&31, row = (r&3)+8*(r>>2)+4*(lane>>5)
#pragma unroll
    for (int r = 0; r < 16; ++r) {
        const int row = (r & 3) + 8 * (r >> 2) + 4 * fo;
        sm[(kh2 * 32 + row) * 68 + cg * 32 + fr32] = acc[r];
    }
    __syncthreads();

    // ---- write 32x64 partial: s=0 -> o_log region of out, s=1 -> part1 ----
    float* dst = s ? part1 : out;
    const int prow = tid >> 3;
    const int pe   = (tid & 7) * 8;
#pragma unroll
    for (int t = 0; t < 8; ++t) {
        const float val = sm[(0 * 32 + prow) * 68 + pe + t]
                        + sm[(1 * 32 + prow) * 68 + pe + t];
        dst[(size_t)(rb + prow) * E_NUM + pe + t] = val;
    }
}

// ---- fin: add partials, mask, logits out, softmax + top-8 + renorm ----
__global__ __launch_bounds__(64) void router_fin(
    const float* __restrict__ part1, const unsigned short* __restrict__ WS,
    float* __restrict__ out)
{
    const int lane = threadIdx.x & 63;
    const int rb   = blockIdx.x * 16;
    const int fr   = lane & 15;
    const int fq   = lane >> 4;

    const unsigned long long mbits =
        *(const unsigned long long*)((const char*)WS + MASK_OFF);

    float* o_log = out;
    float* o_rw  = out + (size_t)T_ROWS * E_NUM;
    float* o_se  = o_rw + (size_t)T_ROWS * TOPK;

#pragma unroll
    for (int j = 0; j < 4; ++j) {
        const int grow = rb + fq * 4 + j;
        const size_t b = (size_t)grow * E_NUM;
        float a0 = o_log[b +  0 + fr] + part1[b +  0 + fr];
        float a1 = o_log[b + 16 + fr] + part1[b + 16 + fr];
        float a2 = o_log[b + 32 + fr] + part1[b + 32 + fr];
        float a3 = o_log[b + 48 + fr] + part1[b + 48 + fr];
        float mv0 = ((mbits >> ( 0 + fr)) & 1) ? a0 : -10000.0f;
        float mv1 = ((mbits >> (16 + fr)) & 1) ? a1 : -10000.0f;
        float mv2 = ((mbits >> (32 + fr)) & 1) ? a2 : -10000.0f;
        float mv3 = ((mbits >> (48 + fr)) & 1) ? a3 : -10000.0f;
        o_log[b +  0 + fr] = mv0;
        o_log[b + 16 + fr] = mv1;
        o_log[b + 32 + fr] = mv2;
        o_log[b + 48 + fr] = mv3;

        float m = fmaxf(fmaxf(mv0, mv1), fmaxf(mv2, mv3));
#pragma unroll
        for (int off = 1; off < 16; off <<= 1) m = fmaxf(m, __shfl_xor(m, off));

        float tsum = 0.f, myv = 0.f;
        int   mye  = 0;
#pragma unroll
        for (int t = 0; t < TOPK; ++t) {
            float bv = mv0; int be = fr;
            if (mv1 > bv) { bv = mv1; be = 16 + fr; }
            if (mv2 > bv) { bv = mv2; be = 32 + fr; }
            if (mv3 > bv) { bv = mv3; be = 48 + fr; }
#pragma unroll
            for (int off = 1; off < 16; off <<= 1) {
                float ov = __shfl_xor(bv, off);
                int   oe = __shfl_xor(be, off);
                if (ov > bv || (ov == bv && oe < be)) { bv = ov; be = oe; }
            }
            const float pv = expf(bv - m);
            tsum += pv;
            if (fr == t) { myv = pv; mye = be; }
            if ((be & 15) == fr) {       // owner lane excludes winner
                const int bn = be >> 4;
                if      (bn == 0) mv0 = -3.4e38f;
                else if (bn == 1) mv1 = -3.4e38f;
                else if (bn == 2) mv2 = -3.4e38f;
                else              mv3 = -3.4e38f;
            }
        }
        if (fr < TOPK) {
            o_rw[(size_t)grow * TOPK + fr] = myv / tsum;
            o_se[(size_t)grow * TOPK + fr] = (float)mye;
        }
    }
}

extern "C" void kernel_launch(void* const* d_in, const int* in_sizes, int n_in,
                              void* d_out, int out_size, void* d_ws, size_t ws_size,
                              hipStream_t stream) {
    const float* X   = (const float*)d_in[0];
    const float* W   = (const float*)d_in[1];
    const int*   ids = (const int*)d_in[2];
    const int    nids = in_sizes[2];
    float* out = (float*)d_out;

    unsigned short* WS    = (unsigned short*)d_ws;          // 1 MB image + mask
    float*          part1 = (float*)((char*)d_ws + PART_OFF); // 4 MB partial

    hipLaunchKernelGGL(prep_w, dim3(256), dim3(256), 0, stream, W, WS, ids, nids);
    hipLaunchKernelGGL(router_part, dim3(T_ROWS / MROWS * 2), dim3(256), 0, stream,
                       X, WS, out, part1);
    hipLaunchKernelGGL(router_fin, dim3(T_ROWS / 16), dim3(64), 0, stream,
                       part1, WS, out);
}

// Round 13
// 93.912 us; speedup vs baseline: 1.1166x; 1.1166x over previous
//
#include <hip/hip_runtime.h>
#include <hip/hip_bf16.h>

typedef __attribute__((ext_vector_type(16))) float f32x16;
typedef __attribute__((ext_vector_type(8))) short short8v;
typedef __attribute__((ext_vector_type(8))) unsigned short ushort8v;

#define T_ROWS 16384
#define H_DIM  4096
#define E_NUM  64
#define TOPK   8
#define MROWS  32               // rows per block
#define KC     128              // k-chunk
#define NCH    (H_DIM / KC)     // 32 chunks
#define WIMG   32768            // bytes per W chunk image (frag-slot-ordered)
#define MASK_OFF ((size_t)NCH * WIMG)

__device__ __forceinline__ unsigned short f2bf(float f) {
    unsigned int u = __float_as_uint(f);
    unsigned int r = (u + 0x7fffu + ((u >> 16) & 1u)) >> 16;  // RNE
    return (unsigned short)r;
}
__device__ __forceinline__ float bf2f(unsigned short h) {
    return __uint_as_float(((unsigned int)h) << 16);
}

// ---- prep: frag-slot-ordered W image + allowed-mask ----
// image[ch 0..31][w 0..7][j 0..3][lane 0..63]*16B ; role w: cg=w&1, kh=w>>1 ;
// slot j: plane=j&1 (hi/lo), ks=j>>1. Value: 8 bf16 of
// W[cg*32+(lane&31)][ch*128 + kh*32 + ks*16 + (lane>>5)*8 ...]
__global__ __launch_bounds__(256) void prep_w(
    const float* __restrict__ W, unsigned short* __restrict__ WS,
    const int* __restrict__ ids, int nids)
{
    const int g    = blockIdx.x * 256 + threadIdx.x;   // 65536 16B-groups
    const int lane = g & 63;
    const int j    = (g >> 6) & 3;
    const int w    = (g >> 8) & 7;
    const int ch   = g >> 11;
    const int plane = j & 1;
    const int ks    = j >> 1;
    const int row   = (w & 1) * 32 + (lane & 31);
    const int kk    = ch * KC + (w >> 1) * 32 + ks * 16 + (lane >> 5) * 8;
    const float* src = W + (size_t)row * H_DIM + kk;
    ushort8v o;
#pragma unroll
    for (int t = 0; t < 8; ++t) {
        const float f = src[t];
        const unsigned short hb = f2bf(f);
        o[t] = (plane == 0) ? hb : f2bf(f - bf2f(hb));
    }
    *(ushort8v*)((char*)WS + (size_t)g * 16) = o;

    if (blockIdx.x == 0 && threadIdx.x == 0) {
        unsigned long long mb = 0;
        for (int t = 0; t < nids; ++t) {
            const int e = ids[t];
            if (e >= 0 && e < E_NUM) mb |= (1ull << e);
        }
        *(unsigned long long*)((char*)WS + MASK_OFF) = mb;
    }
}

// ---- main: 512 thr = 8 waves; wave (cg=w&1, kh=w>>1) computes a 32x32
// partial over K-quarter kh with mfma_32x32x16; B-frags global->regs. ----
__global__ __launch_bounds__(512, 4) void router_main(
    const float* __restrict__ X, const unsigned short* __restrict__ WS,
    float* __restrict__ out)
{
    const int tid  = threadIdx.x;
    const int lane = tid & 63;
    const int w    = tid >> 6;        // 0..7
    const int cg   = w & 1;           // experts half
    const int kh   = w >> 1;          // K quarter of the chunk
    const int rb   = blockIdx.x * MROWS;
    const int fr32 = lane & 31;
    const int fo   = lane >> 5;

    __shared__ char LDSRAW[34816];    // X tiles (16 KB) then scoreboard (34 KB)
    char* XH = LDSRAW;                // 8 KB [32][256B swizzled] bf16-hi
    char* XL = LDSRAW + 8192;         // 8 KB bf16-lo

    // staging coords: X 8 f32/thread
    const int srow = tid >> 4;               // 0..31
    const int sc8  = (tid & 15) * 8;         // f32 col base
    const float* xg = X + (size_t)(rb + srow) * H_DIM + sc8;
    const int xbyte = srow * 256 + ((sc8 * 2) ^ ((srow & 15) << 4));

    // W frag pointer: per wave, per chunk: 4 x 1KB coalesced slots
    const char* wfg = (const char*)WS + (size_t)w * 4096 + (size_t)lane * 16;

    const int arow = fr32;
    const int asw  = (arow & 15) << 4;

    f32x16 acc;
#pragma unroll
    for (int r = 0; r < 16; ++r) acc[r] = 0.f;

    // ---- prologue: chunk-0 registers ----
    float4 px0 = *(const float4*)(xg);
    float4 px1 = *(const float4*)(xg + 4);
    short8v cA0, cA1, cA2, cA3, cB0, cB1, cB2, cB3;
    cA0 = *(const short8v*)(wfg);
    cA1 = *(const short8v*)(wfg + 1024);
    cA2 = *(const short8v*)(wfg + 2048);
    cA3 = *(const short8v*)(wfg + 3072);

#define STEP(CH, C0, C1, C2, C3, N0, N1, N2, N3) do {                        \
        __syncthreads();   /* [A] prev compute done reading LDS */           \
        {                                                                    \
            float v[8] = {px0.x, px0.y, px0.z, px0.w,                        \
                          px1.x, px1.y, px1.z, px1.w};                       \
            ushort8v hv, lv;                                                 \
            _Pragma("unroll")                                                \
            for (int t = 0; t < 8; ++t) {                                    \
                const unsigned short hb = f2bf(v[t]);                        \
                hv[t] = hb;                                                  \
                lv[t] = f2bf(v[t] - bf2f(hb));                               \
            }                                                                \
            *(ushort8v*)(XH + xbyte) = hv;                                   \
            *(ushort8v*)(XL + xbyte) = lv;                                   \
        }                                                                    \
        __syncthreads();   /* [B] X tile ready */                            \
        if ((CH) + 1 < NCH) {                                                \
            const float* xn = xg + ((CH) + 1) * KC;                          \
            px0 = *(const float4*)(xn);                                      \
            px1 = *(const float4*)(xn + 4);                                  \
            const char* wi = wfg + (size_t)((CH) + 1) * WIMG;                \
            N0 = *(const short8v*)(wi);                                      \
            N1 = *(const short8v*)(wi + 1024);                               \
            N2 = *(const short8v*)(wi + 2048);                               \
            N3 = *(const short8v*)(wi + 3072);                               \
        }                                                                    \
        {                                                                    \
            const int kb0 = kh * 64 + fo * 16;                               \
            short8v ah = *(const short8v*)(XH + arow * 256 + (kb0 ^ asw));   \
            short8v al = *(const short8v*)(XL + arow * 256 + (kb0 ^ asw));   \
            acc = __builtin_amdgcn_mfma_f32_32x32x16_bf16(ah, C0, acc, 0, 0, 0); \
            acc = __builtin_amdgcn_mfma_f32_32x32x16_bf16(ah, C1, acc, 0, 0, 0); \
            acc = __builtin_amdgcn_mfma_f32_32x32x16_bf16(al, C0, acc, 0, 0, 0); \
            const int kb1 = kb0 + 32;                                        \
            short8v ah1 = *(const short8v*)(XH + arow * 256 + (kb1 ^ asw));  \
            short8v al1 = *(const short8v*)(XL + arow * 256 + (kb1 ^ asw));  \
            acc = __builtin_amdgcn_mfma_f32_32x32x16_bf16(ah1, C2, acc, 0, 0, 0); \
            acc = __builtin_amdgcn_mfma_f32_32x32x16_bf16(ah1, C3, acc, 0, 0, 0); \
            acc = __builtin_amdgcn_mfma_f32_32x32x16_bf16(al1, C2, acc, 0, 0, 0); \
        }                                                                    \
    } while (0)

    for (int ch = 0; ch < NCH; ch += 2) {
        STEP(ch,     cA0, cA1, cA2, cA3, cB0, cB1, cB2, cB3);
        STEP(ch + 1, cB0, cB1, cB2, cB3, cA0, cA1, cA2, cA3);
    }
#undef STEP

    // ---- scoreboard: 4 kh-planes [4][32][68] f32, deterministic reduce ----
    __syncthreads();                       // all compute done
    float* sm = (float*)LDSRAW;            // 34816 B exactly
    // C/D layout (m74/m101): col = lane&31, row = (r&3)+8*(r>>2)+4*(lane>>5)
#pragma unroll
    for (int r = 0; r < 16; ++r) {
        const int row = (r & 3) + 8 * (r >> 2) + 4 * fo;
        sm[(kh * 32 + row) * 68 + cg * 32 + fr32] = acc[r];
    }
    __syncthreads();
    if (w >= 2) return;                    // no barriers after this point

    const unsigned long long mbits =
        *(const unsigned long long*)((const char*)WS + MASK_OFF);

    const int fr = lane & 15;
    const int fq = lane >> 4;
    float* o_log = out;
    float* o_rw  = out + (size_t)T_ROWS * E_NUM;
    float* o_se  = o_rw + (size_t)T_ROWS * TOPK;

    // wave w handles rows w*16 .. w*16+15 with the value-verified epilogue
#pragma unroll
    for (int j = 0; j < 4; ++j) {
        const int row_l = w * 16 + fq * 4 + j;
        const int grow  = rb + row_l;
        float a0 = 0.f, a1 = 0.f, a2 = 0.f, a3 = 0.f;
#pragma unroll
        for (int p = 0; p < 4; ++p) {      // fixed-order kh reduction
            a0 += sm[(p * 32 + row_l) * 68 +  0 + fr];
            a1 += sm[(p * 32 + row_l) * 68 + 16 + fr];
            a2 += sm[(p * 32 + row_l) * 68 + 32 + fr];
            a3 += sm[(p * 32 + row_l) * 68 + 48 + fr];
        }
        float mv0 = ((mbits >> ( 0 + fr)) & 1) ? a0 : -10000.0f;
        float mv1 = ((mbits >> (16 + fr)) & 1) ? a1 : -10000.0f;
        float mv2 = ((mbits >> (32 + fr)) & 1) ? a2 : -10000.0f;
        float mv3 = ((mbits >> (48 + fr)) & 1) ? a3 : -10000.0f;
        o_log[(size_t)grow * 64 +  0 + fr] = mv0;
        o_log[(size_t)grow * 64 + 16 + fr] = mv1;
        o_log[(size_t)grow * 64 + 32 + fr] = mv2;
        o_log[(size_t)grow * 64 + 48 + fr] = mv3;

        float m = fmaxf(fmaxf(mv0, mv1), fmaxf(mv2, mv3));
#pragma unroll
        for (int off = 1; off < 16; off <<= 1) m = fmaxf(m, __shfl_xor(m, off));

        float tsum = 0.f, myv = 0.f;
        int   mye  = 0;
#pragma unroll
        for (int t = 0; t < TOPK; ++t) {
            float bv = mv0; int be = fr;
            if (mv1 > bv) { bv = mv1; be = 16 + fr; }
            if (mv2 > bv) { bv = mv2; be = 32 + fr; }
            if (mv3 > bv) { bv = mv3; be = 48 + fr; }
#pragma unroll
            for (int off = 1; off < 16; off <<= 1) {
                float ov = __shfl_xor(bv, off);
                int   oe = __shfl_xor(be, off);
                if (ov > bv || (ov == bv && oe < be)) { bv = ov; be = oe; }
            }
            const float pv = expf(bv - m);
            tsum += pv;
            if (fr == t) { myv = pv; mye = be; }
            if ((be & 15) == fr) {       // owner lane excludes winner
                const int bn = be >> 4;
                if      (bn == 0) mv0 = -3.4e38f;
                else if (bn == 1) mv1 = -3.4e38f;
                else if (bn == 2) mv2 = -3.4e38f;
                else              mv3 = -3.4e38f;
            }
        }
        if (fr < TOPK) {
            o_rw[(size_t)grow * TOPK + fr] = myv / tsum;
            o_se[(size_t)grow * TOPK + fr] = (float)mye;
        }
    }
}

extern "C" void kernel_launch(void* const* d_in, const int* in_sizes, int n_in,
                              void* d_out, int out_size, void* d_ws, size_t ws_size,
                              hipStream_t stream) {
    const float* X   = (const float*)d_in[0];
    const float* W   = (const float*)d_in[1];
    const int*   ids = (const int*)d_in[2];
    const int    nids = in_sizes[2];
    float* out = (float*)d_out;

    unsigned short* WS = (unsigned short*)d_ws;   // 1 MB W image + 8 B mask

    hipLaunchKernelGGL(prep_w, dim3(256), dim3(256), 0, stream, W, WS, ids, nids);
    hipLaunchKernelGGL(router_main, dim3(T_ROWS / MROWS), dim3(512), 0, stream,
                       X, WS, out);
}